// Round 1
// baseline (2106.566 us; speedup 1.0000x reference)
//
#include <hip/hip_runtime.h>
#include <cstdint>
#include <cfloat>
#include <cmath>

// Problem constants
#define B_ 8
#define C_ 64
#define N_ 4096
#define O_ 64
#define K_ 20
#define EPS_ 1e-5f
#define SLOPE_ 0.2f

// knn kernel tiling
#define RB 32          // rows per block
#define TN 128         // column tile
#define CAP 160        // candidate buffer capacity per row
#define TCOMP 96       // compact when cnt exceeds this
#define NTILES (N_ / TN)

// workspace layout (float offsets)
#define WS_XX   0                        // B*N                 = 32768
#define WS_PT   32768                    // B*N*O               = 2097152
#define WS_QT   (WS_PT + 2097152)        // B*N*O
#define WS_IDX  (WS_QT + 2097152)        // B*N*K ints          = 655360
#define WS_PART (WS_IDX + 655360)        // 512*128
#define WS_SS   (WS_PART + 65536)        // 128
// total ~4.95M floats ~= 19 MB

__device__ __forceinline__ void lds_fence() {
    asm volatile("s_waitcnt lgkmcnt(0)" ::: "memory");
}

// ---------------------------------------------------------------- K1: ||x_n||^2
__global__ __launch_bounds__(256) void k_xx(const float* __restrict__ x,
                                            float* __restrict__ xx) {
    int i = blockIdx.x * 256 + threadIdx.x;          // 0 .. B*N-1
    int b = i >> 12, n = i & (N_ - 1);
    const float* xb = x + (size_t)b * C_ * N_;
    float s = 0.f;
    #pragma unroll
    for (int c = 0; c < C_; c++) {
        float v = xb[c * N_ + n];
        s = fmaf(v, v, s);                           // same order as knn dot -> self-dist exactly 0
    }
    xx[i] = s;
}

// ---------------------------------------------------------------- K2: top-20 kNN
__global__ __launch_bounds__(256, 2) void k_knn(const float* __restrict__ x,
                                                const float* __restrict__ xx,
                                                int* __restrict__ idxo) {
    __shared__ float rowXT[C_][RB];       // [c][r]
    __shared__ float colX[C_][TN];        // [c][m]
    __shared__ float rowXX[RB];
    __shared__ float colXX[TN];
    __shared__ float bufv[RB][CAP];
    __shared__ unsigned short bufi[RB][CAP];
    __shared__ int   cnt[RB];
    __shared__ int   ovf[RB];
    __shared__ float thr[RB];
    __shared__ float tmpv[4][K_];
    __shared__ unsigned short tmpi[4][K_];

    const int tid = threadIdx.x;
    const int b   = blockIdx.x / (N_ / RB);
    const int n0  = (blockIdx.x % (N_ / RB)) * RB;
    const float* xb = x + (size_t)b * C_ * N_;

    if (tid < RB) {
        cnt[tid] = 0; ovf[tid] = 0; thr[tid] = -INFINITY;
        rowXX[tid] = xx[b * N_ + n0 + tid];
    }
    #pragma unroll
    for (int kk = 0; kk < 8; kk++) {                 // stage 64x32 row block
        int id = tid + kk * 256;
        int c = id >> 5, r = id & 31;
        rowXT[c][r] = xb[c * N_ + n0 + r];
    }
    __syncthreads();

    const int tr   = tid >> 5;   // 0..7 row group (4 rows)
    const int tm   = tid & 31;   // col group (4 cols)
    const int r0   = tr * 4;
    const int wave = tid >> 6;   // 0..3
    const int lane = tid & 63;

    // wave-scope compaction: exact top-20 of buffered candidates by rank selection
    auto compact = [&](int row) {
        const int n = min(cnt[row], CAP);
        float mv[3]; int mi[3]; int rk[3];
        #pragma unroll
        for (int q = 0; q < 3; q++) {
            int e = lane + q * 64;
            bool val = e < n;
            mv[q] = val ? bufv[row][e] : 0.f;
            mi[q] = val ? (int)bufi[row][e] : 0;
            rk[q] = 0;
        }
        for (int jj = 0; jj < n; jj++) {             // broadcast reads
            float jv = bufv[row][jj];
            int   ji = (int)bufi[row][jj];
            #pragma unroll
            for (int q = 0; q < 3; q++)
                rk[q] += (jv > mv[q]) || (jv == mv[q] && ji < mi[q]);
        }
        #pragma unroll
        for (int q = 0; q < 3; q++) {
            int e = lane + q * 64;
            if (e < n && rk[q] < K_) { tmpv[wave][rk[q]] = mv[q]; tmpi[wave][rk[q]] = (unsigned short)mi[q]; }
        }
        lds_fence();
        if (lane < K_) { bufv[row][lane] = tmpv[wave][lane]; bufi[row][lane] = tmpi[wave][lane]; }
        if (lane == 0) { cnt[row] = K_; thr[row] = tmpv[wave][K_ - 1]; }
        lds_fence();
    };

    for (int t = 0; t < NTILES; t++) {
        const int m0 = t * TN;
        __syncthreads();                              // previous tile's readers done
        #pragma unroll
        for (int kk = 0; kk < 8; kk++) {              // stage 64x128 col tile (float4)
            int fid = tid + kk * 256;
            int c = fid >> 5, mq = fid & 31;
            float4 g = *reinterpret_cast<const float4*>(xb + c * N_ + m0 + mq * 4);
            *reinterpret_cast<float4*>(&colX[c][mq * 4]) = g;
        }
        if (tid < TN) colXX[tid] = xx[b * N_ + m0 + tid];
        __syncthreads();

        float acc[4][4] = {};
        #pragma unroll 8
        for (int c = 0; c < C_; c++) {
            float4 rv = *reinterpret_cast<const float4*>(&rowXT[c][r0]);
            float4 cv = *reinterpret_cast<const float4*>(&colX[c][tm * 4]);
            acc[0][0] = fmaf(rv.x, cv.x, acc[0][0]);
            acc[0][1] = fmaf(rv.x, cv.y, acc[0][1]);
            acc[0][2] = fmaf(rv.x, cv.z, acc[0][2]);
            acc[0][3] = fmaf(rv.x, cv.w, acc[0][3]);
            acc[1][0] = fmaf(rv.y, cv.x, acc[1][0]);
            acc[1][1] = fmaf(rv.y, cv.y, acc[1][1]);
            acc[1][2] = fmaf(rv.y, cv.z, acc[1][2]);
            acc[1][3] = fmaf(rv.y, cv.w, acc[1][3]);
            acc[2][0] = fmaf(rv.z, cv.x, acc[2][0]);
            acc[2][1] = fmaf(rv.z, cv.y, acc[2][1]);
            acc[2][2] = fmaf(rv.z, cv.z, acc[2][2]);
            acc[2][3] = fmaf(rv.z, cv.w, acc[2][3]);
            acc[3][0] = fmaf(rv.w, cv.x, acc[3][0]);
            acc[3][1] = fmaf(rv.w, cv.y, acc[3][1]);
            acc[3][2] = fmaf(rv.w, cv.z, acc[3][2]);
            acc[3][3] = fmaf(rv.w, cv.w, acc[3][3]);
        }

        float nd[4][4];
        #pragma unroll
        for (int i = 0; i < 4; i++)
            #pragma unroll
            for (int j = 0; j < 4; j++)
                nd[i][j] = 2.f * acc[i][j] - rowXX[r0 + i] - colXX[tm * 4 + j];

        // append candidates above the per-row threshold
        #pragma unroll
        for (int i = 0; i < 4; i++) {
            const int row = r0 + i;
            const float th = thr[row];
            #pragma unroll
            for (int j = 0; j < 4; j++) {
                const float v = nd[i][j];
                if (v > th) {
                    int slot = atomicAdd(&cnt[row], 1);
                    if (slot < CAP) { bufv[row][slot] = v; bufi[row][slot] = (unsigned short)(m0 + tm * 4 + j); }
                    else ovf[row] = 1;
                }
            }
        }
        lds_fence();

        // per-wave maintenance of its 8 rows
        for (int rr = 0; rr < 8; rr++) {
            const int row = wave * 8 + rr;
            const int c0 = cnt[row];
            const int of = ovf[row];
            if (c0 > TCOMP || of) {
                compact(row);
                if (of) {                              // rare: re-append lost tile candidates (dedup'd)
                    if (lane == 0) ovf[row] = 0;
                    lds_fence();
                    const float th2 = thr[row];
                    const int i = row & 3;
                    const bool mine = ((row >> 2) == tr);
                    #pragma unroll
                    for (int j = 0; j < 4; j++) {
                        float v = mine ? nd[i][j] : -INFINITY;
                        bool add = v > th2;
                        if (add) {
                            int myidx = m0 + tm * 4 + j;
                            for (int e = 0; e < K_; e++)
                                if (bufi[row][e] == (unsigned short)myidx) add = false;
                        }
                        if (add) {
                            int slot = atomicAdd(&cnt[row], 1);   // 20 + <=128 <= CAP, can't overflow
                            bufv[row][slot] = v; bufi[row][slot] = (unsigned short)(m0 + tm * 4 + j);
                        }
                    }
                    lds_fence();
                }
            }
        }
    }

    // final exact top-20 + write indices
    for (int rr = 0; rr < 8; rr++) {
        const int row = wave * 8 + rr;
        compact(row);
        if (lane < K_) idxo[((size_t)(b * N_ + n0 + row)) * K_ + lane] = (int)bufi[row][lane];
    }
}

// ---------------------------------------------------------------- K3: Pt = W1^T x, Qt = (W2-W1)^T x  (transposed [b][n][o])
__global__ __launch_bounds__(256) void k_pq(const float* __restrict__ x,
                                            const float* __restrict__ W,
                                            float* __restrict__ Pt,
                                            float* __restrict__ Qt) {
    __shared__ float2 Wl[64][65];   // [c][o] = (W1, W2-W1), padded
    __shared__ float  xT[64][64];   // [c][n_local]
    const int tid = threadIdx.x;
    const int b  = blockIdx.x >> 6;
    const int n0 = (blockIdx.x & 63) * 64;
    const float* xb = x + (size_t)b * C_ * N_;

    #pragma unroll
    for (int kk = 0; kk < 16; kk++) {
        int id = tid + kk * 256;
        int c = id >> 6, o = id & 63;
        float w1 = W[o * 128 + c];
        float w2 = W[o * 128 + 64 + c];
        Wl[c][o] = make_float2(w1, w2 - w1);
    }
    #pragma unroll
    for (int kk = 0; kk < 16; kk++) {
        int id = tid + kk * 256;
        int c = id >> 6, nl = id & 63;
        xT[c][nl] = xb[c * N_ + n0 + nl];
    }
    __syncthreads();

    const int o = tid & 63, nq = tid >> 6;
    for (int s2 = 0; s2 < 4; s2++) {
        int g = s2 * 4 + nq;                          // n-group of 4
        float a1[4] = {0, 0, 0, 0}, a2[4] = {0, 0, 0, 0};
        #pragma unroll 8
        for (int c = 0; c < 64; c++) {
            float4 xv = *reinterpret_cast<const float4*>(&xT[c][g * 4]);  // broadcast
            float2 wv = Wl[c][o];
            a1[0] = fmaf(wv.x, xv.x, a1[0]); a2[0] = fmaf(wv.y, xv.x, a2[0]);
            a1[1] = fmaf(wv.x, xv.y, a1[1]); a2[1] = fmaf(wv.y, xv.y, a2[1]);
            a1[2] = fmaf(wv.x, xv.z, a1[2]); a2[2] = fmaf(wv.y, xv.z, a2[2]);
            a1[3] = fmaf(wv.x, xv.w, a1[3]); a2[3] = fmaf(wv.y, xv.w, a2[3]);
        }
        #pragma unroll
        for (int gg = 0; gg < 4; gg++) {
            size_t base = ((size_t)(b * N_ + n0 + g * 4 + gg)) * O_ + o;
            Pt[base] = a1[gg];
            Qt[base] = a2[gg];
        }
    }
}

// ---------------------------------------------------------------- K4: partial sums for BN stats
__global__ __launch_bounds__(256) void k_stats(const float* __restrict__ Pt,
                                               const float* __restrict__ Qt,
                                               const int* __restrict__ idxb,
                                               float* __restrict__ part) {
    const int tid = threadIdx.x;
    const int o = tid & 63, w = tid >> 6;
    float s = 0.f, q = 0.f;
    for (int it = 0; it < 16; it++) {
        int p = blockIdx.x * 4 + w + it * 2048;       // flat (b,n)
        int b = p >> 12;
        const float* Ptb = Pt + (size_t)b * (N_ * O_);
        float Q = Qt[(size_t)p * O_ + o];
        const int* ip = idxb + (size_t)p * K_;
        #pragma unroll
        for (int k = 0; k < K_; k++) {
            int m = ip[k];
            float v = Ptb[m * O_ + o] + Q;
            s += v;
            q = fmaf(v, v, q);
        }
    }
    __shared__ float ps[4][64], pq2[4][64];
    ps[w][o] = s; pq2[w][o] = q;
    __syncthreads();
    if (tid < 64) {
        float S  = ps[0][tid] + ps[1][tid] + ps[2][tid] + ps[3][tid];
        float Qq = pq2[0][tid] + pq2[1][tid] + pq2[2][tid] + pq2[3][tid];
        part[blockIdx.x * 128 + tid]      = S;
        part[blockIdx.x * 128 + 64 + tid] = Qq;
    }
}

// ---------------------------------------------------------------- K5: finalize mean/var -> scale/shift
__global__ void k_finalize(const float* __restrict__ part,
                           const float* __restrict__ gamma,
                           const float* __restrict__ beta,
                           float* __restrict__ ss) {
    int o = threadIdx.x;
    if (o < 64) {
        double s = 0.0, q = 0.0;
        for (int blk = 0; blk < 512; blk++) {
            s += part[blk * 128 + o];
            q += part[blk * 128 + 64 + o];
        }
        double M = (double)B_ * N_ * K_;
        double mean = s / M;
        double var = q / M - mean * mean;
        double inv = 1.0 / sqrt(var + (double)EPS_);
        double sc = (double)gamma[o] * inv;
        ss[o]      = (float)sc;
        ss[64 + o] = (float)((double)beta[o] - mean * sc);
    }
}

// ---------------------------------------------------------------- K6: normalized leaky-relu max over K, coalesced store
__global__ __launch_bounds__(256) void k_out(const float* __restrict__ Pt,
                                             const float* __restrict__ Qt,
                                             const int* __restrict__ idxb,
                                             const float* __restrict__ ss,
                                             float* __restrict__ out) {
    __shared__ float res[64][65];
    const int tid = threadIdx.x;
    const int o = tid & 63, w = tid >> 6;
    const int b  = blockIdx.x >> 6;
    const int n0 = (blockIdx.x & 63) * 64;
    const float sc = ss[o], sh = ss[64 + o];
    const float* Ptb = Pt + (size_t)b * (N_ * O_);
    for (int s2 = 0; s2 < 16; s2++) {
        int nl = s2 * 4 + w;
        int p = b * N_ + n0 + nl;
        float Q = Qt[(size_t)p * O_ + o];
        const int* ip = idxb + (size_t)p * K_;
        float best = -FLT_MAX;
        #pragma unroll
        for (int k = 0; k < K_; k++) {
            int m = ip[k];
            float v = Ptb[m * O_ + o] + Q;
            float t2 = fmaf(v, sc, sh);
            t2 = t2 >= 0.f ? t2 : SLOPE_ * t2;
            best = fmaxf(best, t2);
        }
        res[nl][o] = best;
    }
    __syncthreads();
    const int j = tid & 63;
    const int ow = tid >> 6;
    for (int s2 = 0; s2 < 16; s2++) {
        int oo = s2 * 4 + ow;
        out[((size_t)(b * O_ + oo)) * N_ + n0 + j] = res[j][oo];
    }
}

// ---------------------------------------------------------------- launch
extern "C" void kernel_launch(void* const* d_in, const int* in_sizes, int n_in,
                              void* d_out, int out_size, void* d_ws, size_t ws_size,
                              hipStream_t stream) {
    const float* x     = (const float*)d_in[0];
    const float* W     = (const float*)d_in[1];
    const float* gamma = (const float*)d_in[2];
    const float* beta  = (const float*)d_in[3];

    float* ws   = (float*)d_ws;
    float* xx   = ws + WS_XX;
    float* Pt   = ws + WS_PT;
    float* Qt   = ws + WS_QT;
    int*   idxb = (int*)(ws + WS_IDX);
    float* part = ws + WS_PART;
    float* ss   = ws + WS_SS;
    float* out  = (float*)d_out;

    hipLaunchKernelGGL(k_xx,       dim3(128),  dim3(256), 0, stream, x, xx);
    hipLaunchKernelGGL(k_pq,       dim3(512),  dim3(256), 0, stream, x, W, Pt, Qt);
    hipLaunchKernelGGL(k_knn,      dim3(1024), dim3(256), 0, stream, x, xx, idxb);
    hipLaunchKernelGGL(k_stats,    dim3(512),  dim3(256), 0, stream, Pt, Qt, idxb, part);
    hipLaunchKernelGGL(k_finalize, dim3(1),    dim3(64),  0, stream, part, gamma, beta, ss);
    hipLaunchKernelGGL(k_out,      dim3(512),  dim3(256), 0, stream, Pt, Qt, idxb, ss, out);
}

// Round 2
// 614.016 us; speedup vs baseline: 3.4308x; 3.4308x over previous
//
#include <hip/hip_runtime.h>
#include <hip/hip_fp16.h>
#include <cstdint>
#include <cfloat>
#include <cmath>

// Problem constants
#define B_ 8
#define C_ 64
#define N_ 4096
#define O_ 64
#define K_ 20
#define EPS_ 1e-5f
#define SLOPE_ 0.2f

// knn mfma kernel
#define RM 64          // rows per block
#define NT 64          // number of 64-wide column tiles
#define CAP 160        // candidate buffer capacity per row
#define TCOMP 96       // compact when cnt exceeds this
#define MARGIN 1.0f    // approx-distance safety margin (bf16 dot + f16 key quant)
#define RCAP 48        // candidates carried to exact re-rank

typedef __attribute__((ext_vector_type(8))) short bf16x8;
typedef __attribute__((ext_vector_type(4))) float f32x4;

// workspace layout (float offsets)
#define WS_IDXB 0                 // B*N*K ints = 655360
#define WS_R1   655360            // XTf fp32 [b][n][c] = 2097152; later aliased by Pt
#define WS_R2   2752512           // region2 = 2097152 floats; later aliased by Qt
#define R2_XTH   0                // XTh bf16 [b][n][c]: 2097152 u16 = 1048576 fl
#define R2_CANDS 1048576          // cands u16 [32768][48] = 1572864 u16 = 786432 fl
#define R2_CCNT  1835008          // 32768 ints
#define R2_XX    1867776          // 32768 floats (ends 1900544 < 2097152)
#define WS_PART 4849664           // 512*128
#define WS_SS   4915200           // 128
// end = 4915328 floats = 19.66 MB

__device__ __forceinline__ void lds_fence() {
    asm volatile("s_waitcnt lgkmcnt(0)" ::: "memory");
}
__device__ __forceinline__ unsigned short f2bf(float f) {      // RNE float->bf16
    union { float f; unsigned int u; } v; v.f = f;
    unsigned int r = v.u + 0x7FFF + ((v.u >> 16) & 1);
    return (unsigned short)(r >> 16);
}
__device__ __forceinline__ unsigned short flip16(unsigned short h) {  // order-preserving f16->u16
    return h ^ ((h & 0x8000) ? 0xFFFFu : 0x8000u);
}
__device__ __forceinline__ float keyval(unsigned int key) {
    unsigned short f = (unsigned short)(key >> 16);
    unsigned short orig = (f & 0x8000) ? (unsigned short)(f ^ 0x8000) : (unsigned short)(f ^ 0xFFFF);
    return __half2float(__ushort_as_half(orig));
}

// ---------------------------------------------------------------- K0: transpose + bf16 + norms
__global__ __launch_bounds__(256) void k_prep(const float* __restrict__ x,
                                              float* __restrict__ XTf,
                                              unsigned short* __restrict__ XTh,
                                              float* __restrict__ xx) {
    __shared__ float xs[64][65];
    const int tid = threadIdx.x;
    const int b = blockIdx.x >> 6, n0 = (blockIdx.x & 63) << 6;
    const float* xb = x + (size_t)b * C_ * N_;
    #pragma unroll
    for (int it = 0; it < 16; it++) {
        int id = it * 256 + tid; int c = id >> 6, nl = id & 63;
        xs[c][nl] = xb[c * N_ + n0 + nl];
    }
    __syncthreads();
    #pragma unroll
    for (int it = 0; it < 4; it++) {
        int flat = it * 256 + tid; int row = flat >> 4, f4 = flat & 15;
        float v0 = xs[f4*4+0][row], v1 = xs[f4*4+1][row], v2 = xs[f4*4+2][row], v3 = xs[f4*4+3][row];
        size_t base = ((size_t)(b * N_ + n0 + row)) * 64 + f4 * 4;
        float4 fv; fv.x = v0; fv.y = v1; fv.z = v2; fv.w = v3;
        *reinterpret_cast<float4*>(XTf + base) = fv;
        ushort4 hv; hv.x = f2bf(v0); hv.y = f2bf(v1); hv.z = f2bf(v2); hv.w = f2bf(v3);
        *reinterpret_cast<ushort4*>(XTh + base) = hv;
    }
    if (tid < 64) {
        float s = 0.f;
        #pragma unroll
        for (int c = 0; c < 64; c++) { float v = xs[c][tid]; s = fmaf(v, v, s); }
        xx[b * N_ + n0 + tid] = s;
    }
}

// ---------------------------------------------------------------- K1: MFMA approx distances + margin top-k candidates
__global__ __launch_bounds__(256, 2) void k_knn2(const unsigned short* __restrict__ XTh,
                                                 const float* __restrict__ xx,
                                                 unsigned short* __restrict__ cands,
                                                 int* __restrict__ ccnt) {
    __shared__ unsigned short At[4096];        // 64x64 bf16, XOR-swizzled
    __shared__ unsigned short Bt[2][4096];     // double-buffered col tiles
    __shared__ unsigned int buf[RM][CAP];      // packed (flip16(f16(nd))<<16 | (4095-m))
    __shared__ float xxr[RM];
    __shared__ float xxc[2][64];
    __shared__ float thr[RM];
    __shared__ int   cnt[RM];
    __shared__ unsigned int tkey[4];

    const int tid = threadIdx.x;
    const int wid = tid >> 6, lane = tid & 63;
    const int g = lane >> 4, lr = lane & 15;
    const int b = blockIdx.x >> 6, rb = blockIdx.x & 63;
    const int n0 = rb << 6;
    const unsigned short* Xb = XTh + (size_t)b * N_ * 64;
    const float* xxb = xx + b * N_;

    // stage A tile (rows n0..n0+63), swizzled: chunk u -> row u>>3, 16B-chunk u&7
    #pragma unroll
    for (int it = 0; it < 2; it++) {
        int u = it * 256 + tid;
        uint4 gv = *reinterpret_cast<const uint4*>(reinterpret_cast<const char*>(Xb) + (size_t)n0 * 128 + (size_t)u * 16);
        int r = u >> 3, cc = u & 7;
        *reinterpret_cast<uint4*>(reinterpret_cast<char*>(At) + r * 128 + ((cc * 16) ^ ((r & 7) << 4))) = gv;
    }
    {   // stage B tile 0 (diagonal start: mt = rb)
        int m0 = rb << 6;
        #pragma unroll
        for (int it = 0; it < 2; it++) {
            int u = it * 256 + tid;
            uint4 gv = *reinterpret_cast<const uint4*>(reinterpret_cast<const char*>(Xb) + (size_t)m0 * 128 + (size_t)u * 16);
            int r = u >> 3, cc = u & 7;
            *reinterpret_cast<uint4*>(reinterpret_cast<char*>(Bt[0]) + r * 128 + ((cc * 16) ^ ((r & 7) << 4))) = gv;
        }
        if (tid < 64) xxc[0][tid] = xxb[m0 + tid];
    }
    if (tid < RM) { xxr[tid] = xxb[n0 + tid]; thr[tid] = -3.0e38f; cnt[tid] = 0; }
    __syncthreads();

    // A fragments, register-resident for the whole sweep
    bf16x8 af[4][2];
    #pragma unroll
    for (int rt = 0; rt < 4; rt++)
        #pragma unroll
        for (int kf = 0; kf < 2; kf++) {
            int row = rt * 16 + lr;
            int off = row * 128 + (((kf << 6) + (g << 4)) ^ ((row & 7) << 4));
            af[rt][kf] = *reinterpret_cast<const bf16x8*>(reinterpret_cast<const char*>(At) + off);
        }

    // wave-wide: exact rank-selection of 20th key, threshold = v20 - MARGIN, drop below-thr
    auto compact = [&](int row, bool emit) {
        int n = cnt[row]; if (n > CAP) n = CAP;
        unsigned int k0 = (lane       < n) ? buf[row][lane]       : 0u;
        unsigned int k1 = (lane + 64  < n) ? buf[row][lane + 64]  : 0u;
        unsigned int k2 = (lane + 128 < n) ? buf[row][lane + 128] : 0u;
        int r0 = 0, r1 = 0, r2 = 0;
        for (int j = 0; j < n; j++) {
            unsigned int kj = buf[row][j];      // broadcast read
            r0 += kj > k0; r1 += kj > k1; r2 += kj > k2;
        }
        if (lane       < n && r0 == K_ - 1) tkey[wid] = k0;
        if (lane + 64  < n && r1 == K_ - 1) tkey[wid] = k1;
        if (lane + 128 < n && r2 == K_ - 1) tkey[wid] = k2;
        lds_fence();
        float th = keyval(tkey[wid]) - MARGIN;
        unsigned int thk = ((unsigned int)flip16(__half_as_ushort(__float2half(th)))) << 16;
        bool p0 = (lane       < n) && (k0 >= thk);
        bool p1 = (lane + 64  < n) && (k1 >= thk);
        bool p2 = (lane + 128 < n) && (k2 >= thk);
        if (p0) buf[row][r0] = k0;    // kept ranks form a prefix (key order = val desc, idx asc)
        if (p1) buf[row][r1] = k1;
        if (p2) buf[row][r2] = k2;
        int nk = __popcll(__ballot(p0)) + __popcll(__ballot(p1)) + __popcll(__ballot(p2));
        if (lane == 0) { cnt[row] = nk; thr[row] = th; }
        if (emit) {
            size_t grow = (size_t)(b * N_ + n0 + row);
            if (p0 && r0 < RCAP) cands[grow * RCAP + r0] = (unsigned short)(4095 - (int)(k0 & 0xFFFFu));
            if (p1 && r1 < RCAP) cands[grow * RCAP + r1] = (unsigned short)(4095 - (int)(k1 & 0xFFFFu));
            if (p2 && r2 < RCAP) cands[grow * RCAP + r2] = (unsigned short)(4095 - (int)(k2 & 0xFFFFu));
            if (lane == 0) ccnt[grow] = nk < RCAP ? nk : RCAP;
        }
        lds_fence();
    };

    int mt = rb;
    for (int t = 0; t < NT; t++) {
        const int cur = t & 1, nxt = cur ^ 1;
        const int m0 = mt << 6;
        const int m0n = ((rb + t + 1) & 63) << 6;
        // issue next-tile staging loads early (latency hides under MFMA+epilogue)
        uint4 g0, g1; float xcn = 0.f;
        if (t + 1 < NT) {
            g0 = *reinterpret_cast<const uint4*>(reinterpret_cast<const char*>(Xb) + (size_t)m0n * 128 + (size_t)tid * 16);
            g1 = *reinterpret_cast<const uint4*>(reinterpret_cast<const char*>(Xb) + (size_t)m0n * 128 + (size_t)(256 + tid) * 16);
            if (tid < 64) xcn = xxb[m0n + tid];
        }
        // B fragments for this wave's 16 columns
        const unsigned short* Bc = Bt[cur];
        int brow = (wid << 4) + lr;
        bf16x8 b0 = *reinterpret_cast<const bf16x8*>(reinterpret_cast<const char*>(Bc) + brow * 128 + (((g << 4)     ) ^ ((brow & 7) << 4)));
        bf16x8 b1 = *reinterpret_cast<const bf16x8*>(reinterpret_cast<const char*>(Bc) + brow * 128 + (((g << 4) + 64) ^ ((brow & 7) << 4)));
        f32x4 acc[4];
        #pragma unroll
        for (int rt = 0; rt < 4; rt++) {
            acc[rt] = {0.f, 0.f, 0.f, 0.f};
            acc[rt] = __builtin_amdgcn_mfma_f32_16x16x32_bf16(af[rt][0], b0, acc[rt], 0, 0, 0);
            acc[rt] = __builtin_amdgcn_mfma_f32_16x16x32_bf16(af[rt][1], b1, acc[rt], 0, 0, 0);
        }
        // epilogue: nd = 2*dot - xx_n - xx_m, threshold-append
        int mcol = m0 + (wid << 4) + lr;
        float xm = xxc[cur][(wid << 4) + lr];
        #pragma unroll
        for (int rt = 0; rt < 4; rt++) {
            #pragma unroll
            for (int q = 0; q < 4; q++) {
                int row = rt * 16 + g * 4 + q;       // verified C/D layout: col=lane&15, row=(lane>>4)*4+reg
                float nd = 2.f * acc[rt][q] - xxr[row] - xm;
                if (nd > thr[row]) {
                    int pos = atomicAdd(&cnt[row], 1);
                    if (pos < CAP) {
                        unsigned int key = ((unsigned int)flip16(__half_as_ushort(__float2half(nd))) << 16)
                                         | (unsigned int)(4095 - mcol);
                        buf[row][pos] = key;
                    }
                }
            }
        }
        __syncthreads();                               // appends visible
        for (int rr = 0; rr < 16; rr++) {              // wave maintains its own 16 rows
            int row = (wid << 4) + rr;
            if (t == 0 || cnt[row] > TCOMP) compact(row, false);
        }
        if (t + 1 < NT) {                              // write prefetched tile
            int u0 = tid, u1 = 256 + tid;
            { int r = u0 >> 3, cc = u0 & 7; *reinterpret_cast<uint4*>(reinterpret_cast<char*>(Bt[nxt]) + r * 128 + ((cc * 16) ^ ((r & 7) << 4))) = g0; }
            { int r = u1 >> 3, cc = u1 & 7; *reinterpret_cast<uint4*>(reinterpret_cast<char*>(Bt[nxt]) + r * 128 + ((cc * 16) ^ ((r & 7) << 4))) = g1; }
            if (tid < 64) xxc[nxt][tid] = xcn;
        }
        __syncthreads();                               // staged tile + maintenance done
        mt = (mt + 1) & 63;
    }
    for (int rr = 0; rr < 16; rr++) {
        int row = (wid << 4) + rr;
        compact(row, true);                            // final: emit candidate set
    }
}

// ---------------------------------------------------------------- K2: exact fp32 re-rank of candidates -> top-20 indices
__global__ __launch_bounds__(256) void k_rerank(const float* __restrict__ XTf,
                                                const float* __restrict__ xx,
                                                const unsigned short* __restrict__ cands,
                                                const int* __restrict__ ccnt,
                                                int* __restrict__ idxb) {
    __shared__ float vals[4][RCAP];
    __shared__ int   ms[4][RCAP];
    const int tid = threadIdx.x, wid = tid >> 6, lane = tid & 63;
    const size_t row = (size_t)blockIdx.x * 4 + wid;
    const int b = (int)(row >> 12), n = (int)(row & 4095);
    const int cn = ccnt[row];
    float nd = -FLT_MAX; int m = 0x7FFFFFFF;
    if (lane < cn) {
        m = cands[row * RCAP + lane];
        const float* xn = XTf + ((size_t)b * N_ + n) * 64;
        const float* xm = XTf + ((size_t)b * N_ + m) * 64;
        float s = 0.f;
        #pragma unroll
        for (int i = 0; i < 16; i++) {
            float4 a  = *reinterpret_cast<const float4*>(xn + i * 4);
            float4 c2 = *reinterpret_cast<const float4*>(xm + i * 4);
            s = fmaf(a.x, c2.x, s); s = fmaf(a.y, c2.y, s);
            s = fmaf(a.z, c2.z, s); s = fmaf(a.w, c2.w, s);
        }
        nd = 2.f * s - xx[b * N_ + n] - xx[b * N_ + m];
        vals[wid][lane] = nd; ms[wid][lane] = m;
    }
    lds_fence();
    if (lane < cn) {
        int rank = 0;
        for (int j = 0; j < cn; j++) {
            float vj = vals[wid][j]; int mj = ms[wid][j];
            rank += (vj > nd) || (vj == nd && mj < m);
        }
        if (rank < K_) idxb[row * K_ + rank] = m;
    }
}

// ---------------------------------------------------------------- K3: Pt = W1^T x, Qt = (W2-W1)^T x  (transposed [b][n][o])
__global__ __launch_bounds__(256) void k_pq(const float* __restrict__ x,
                                            const float* __restrict__ W,
                                            float* __restrict__ Pt,
                                            float* __restrict__ Qt) {
    __shared__ float2 Wl[64][65];
    __shared__ float  xT[64][64];
    const int tid = threadIdx.x;
    const int b  = blockIdx.x >> 6;
    const int n0 = (blockIdx.x & 63) * 64;
    const float* xb = x + (size_t)b * C_ * N_;

    #pragma unroll
    for (int kk = 0; kk < 16; kk++) {
        int id = tid + kk * 256;
        int c = id >> 6, o = id & 63;
        float w1 = W[o * 128 + c];
        float w2 = W[o * 128 + 64 + c];
        Wl[c][o] = make_float2(w1, w2 - w1);
    }
    #pragma unroll
    for (int kk = 0; kk < 16; kk++) {
        int id = tid + kk * 256;
        int c = id >> 6, nl = id & 63;
        xT[c][nl] = xb[c * N_ + n0 + nl];
    }
    __syncthreads();

    const int o = tid & 63, nq = tid >> 6;
    for (int s2 = 0; s2 < 4; s2++) {
        int gq = s2 * 4 + nq;
        float a1[4] = {0, 0, 0, 0}, a2[4] = {0, 0, 0, 0};
        #pragma unroll 8
        for (int c = 0; c < 64; c++) {
            float4 xv = *reinterpret_cast<const float4*>(&xT[c][gq * 4]);
            float2 wv = Wl[c][o];
            a1[0] = fmaf(wv.x, xv.x, a1[0]); a2[0] = fmaf(wv.y, xv.x, a2[0]);
            a1[1] = fmaf(wv.x, xv.y, a1[1]); a2[1] = fmaf(wv.y, xv.y, a2[1]);
            a1[2] = fmaf(wv.x, xv.z, a1[2]); a2[2] = fmaf(wv.y, xv.z, a2[2]);
            a1[3] = fmaf(wv.x, xv.w, a1[3]); a2[3] = fmaf(wv.y, xv.w, a2[3]);
        }
        #pragma unroll
        for (int gg = 0; gg < 4; gg++) {
            size_t base = ((size_t)(b * N_ + n0 + gq * 4 + gg)) * O_ + o;
            Pt[base] = a1[gg];
            Qt[base] = a2[gg];
        }
    }
}

// ---------------------------------------------------------------- K4: partial sums for BN stats
__global__ __launch_bounds__(256) void k_stats(const float* __restrict__ Pt,
                                               const float* __restrict__ Qt,
                                               const int* __restrict__ idxb,
                                               float* __restrict__ part) {
    const int tid = threadIdx.x;
    const int o = tid & 63, w = tid >> 6;
    float s = 0.f, q = 0.f;
    for (int it = 0; it < 16; it++) {
        int p = blockIdx.x * 4 + w + it * 2048;
        int b = p >> 12;
        const float* Ptb = Pt + (size_t)b * (N_ * O_);
        float Q = Qt[(size_t)p * O_ + o];
        const int* ip = idxb + (size_t)p * K_;
        #pragma unroll
        for (int k = 0; k < K_; k++) {
            int m = ip[k];
            float v = Ptb[m * O_ + o] + Q;
            s += v;
            q = fmaf(v, v, q);
        }
    }
    __shared__ float ps[4][64], pq2[4][64];
    ps[w][o] = s; pq2[w][o] = q;
    __syncthreads();
    if (tid < 64) {
        float S  = ps[0][tid] + ps[1][tid] + ps[2][tid] + ps[3][tid];
        float Qq = pq2[0][tid] + pq2[1][tid] + pq2[2][tid] + pq2[3][tid];
        part[blockIdx.x * 128 + tid]      = S;
        part[blockIdx.x * 128 + 64 + tid] = Qq;
    }
}

// ---------------------------------------------------------------- K5: finalize mean/var -> scale/shift
__global__ void k_finalize(const float* __restrict__ part,
                           const float* __restrict__ gamma,
                           const float* __restrict__ beta,
                           float* __restrict__ ss) {
    int o = threadIdx.x;
    if (o < 64) {
        double s = 0.0, q = 0.0;
        for (int blk = 0; blk < 512; blk++) {
            s += part[blk * 128 + o];
            q += part[blk * 128 + 64 + o];
        }
        double M = (double)B_ * N_ * K_;
        double mean = s / M;
        double var = q / M - mean * mean;
        double inv = 1.0 / sqrt(var + (double)EPS_);
        double sc = (double)gamma[o] * inv;
        ss[o]      = (float)sc;
        ss[64 + o] = (float)((double)beta[o] - mean * sc);
    }
}

// ---------------------------------------------------------------- K6: normalized leaky-relu max over K, coalesced store
__global__ __launch_bounds__(256) void k_out(const float* __restrict__ Pt,
                                             const float* __restrict__ Qt,
                                             const int* __restrict__ idxb,
                                             const float* __restrict__ ss,
                                             float* __restrict__ out) {
    __shared__ float res[64][65];
    const int tid = threadIdx.x;
    const int o = tid & 63, w = tid >> 6;
    const int b  = blockIdx.x >> 6;
    const int n0 = (blockIdx.x & 63) * 64;
    const float sc = ss[o], sh = ss[64 + o];
    const float* Ptb = Pt + (size_t)b * (N_ * O_);
    for (int s2 = 0; s2 < 16; s2++) {
        int nl = s2 * 4 + w;
        int p = b * N_ + n0 + nl;
        float Q = Qt[(size_t)p * O_ + o];
        const int* ip = idxb + (size_t)p * K_;
        float best = -FLT_MAX;
        #pragma unroll
        for (int k = 0; k < K_; k++) {
            int m = ip[k];
            float v = Ptb[m * O_ + o] + Q;
            float t2 = fmaf(v, sc, sh);
            t2 = t2 >= 0.f ? t2 : SLOPE_ * t2;
            best = fmaxf(best, t2);
        }
        res[nl][o] = best;
    }
    __syncthreads();
    const int j = tid & 63;
    const int ow = tid >> 6;
    for (int s2 = 0; s2 < 16; s2++) {
        int oo = s2 * 4 + ow;
        out[((size_t)(b * O_ + oo)) * N_ + n0 + j] = res[j][oo];
    }
}

// ---------------------------------------------------------------- launch
extern "C" void kernel_launch(void* const* d_in, const int* in_sizes, int n_in,
                              void* d_out, int out_size, void* d_ws, size_t ws_size,
                              hipStream_t stream) {
    const float* x     = (const float*)d_in[0];
    const float* W     = (const float*)d_in[1];
    const float* gamma = (const float*)d_in[2];
    const float* beta  = (const float*)d_in[3];

    float* ws = (float*)d_ws;
    int*   idxb = (int*)(ws + WS_IDXB);
    float* XTf  = ws + WS_R1;                              // aliased by Pt later
    float* R2   = ws + WS_R2;                              // aliased by Qt later
    unsigned short* XTh   = (unsigned short*)(R2 + R2_XTH);
    unsigned short* cands = (unsigned short*)(R2 + R2_CANDS);
    int*   ccnt = (int*)(R2 + R2_CCNT);
    float* xx   = R2 + R2_XX;
    float* Pt   = ws + WS_R1;
    float* Qt   = ws + WS_R2;
    float* part = ws + WS_PART;
    float* ss   = ws + WS_SS;
    float* out  = (float*)d_out;

    hipLaunchKernelGGL(k_prep,     dim3(512),  dim3(256), 0, stream, x, XTf, XTh, xx);
    hipLaunchKernelGGL(k_knn2,     dim3(512),  dim3(256), 0, stream, XTh, xx, cands, ccnt);
    hipLaunchKernelGGL(k_rerank,   dim3(8192), dim3(256), 0, stream, XTf, xx, cands, ccnt, idxb);
    hipLaunchKernelGGL(k_pq,       dim3(512),  dim3(256), 0, stream, x, W, Pt, Qt);
    hipLaunchKernelGGL(k_stats,    dim3(512),  dim3(256), 0, stream, Pt, Qt, idxb, part);
    hipLaunchKernelGGL(k_finalize, dim3(1),    dim3(64),  0, stream, part, gamma, beta, ss);
    hipLaunchKernelGGL(k_out,      dim3(512),  dim3(256), 0, stream, Pt, Qt, idxb, ss, out);
}

// Round 4
// 384.147 us; speedup vs baseline: 5.4837x; 1.5984x over previous
//
#include <hip/hip_runtime.h>
#include <hip/hip_fp16.h>
#include <cstdint>
#include <cfloat>
#include <cmath>

// Problem constants
#define B_ 8
#define C_ 64
#define N_ 4096
#define O_ 64
#define K_ 20
#define EPS_ 1e-5f
#define SLOPE_ 0.2f

// knn mfma kernel
#define NT 64          // number of 64-wide column tiles
#define CAPK 128       // candidate buffer capacity per row
#define BSTRIDE 132    // buf row stride in words
#define TRIG 64        // compact when cnt exceeds this (appends/tile <= 64 -> no read-OOB)
#define MARGIN 1.0f    // approx-distance safety margin (bf16 dot + f16 key quant)
#define RCAP 48        // candidates carried to exact re-rank

typedef __attribute__((ext_vector_type(8))) short bf16x8;
typedef __attribute__((ext_vector_type(4))) float f32x4;

// workspace layout (float offsets)
#define WS_IDXB 0                 // B*N*K ints = 655360
#define WS_R1   655360            // XTf fp32 [b][n][c] = 2097152; later aliased by Pt
#define WS_R2   2752512           // region2 = 2097152 floats; later aliased by Qt
#define R2_XTH   0                // XTh bf16 [b][n][c]: 2097152 u16 = 1048576 fl
#define R2_CANDS 1048576          // cands u16 [32768][48] = 1572864 u16 = 786432 fl
#define R2_CCNT  1835008          // 32768 ints
#define R2_XX    1867776          // 32768 floats (ends 1900544 < 2097152)
#define WS_PART 4849664           // 512*128
#define WS_SS   4915200           // 128
// end = 4915328 floats = 19.66 MB

__device__ __forceinline__ void lds_fence() {
    asm volatile("s_waitcnt lgkmcnt(0)" ::: "memory");
}
__device__ __forceinline__ unsigned short f2bf(float f) {      // RNE float->bf16
    union { float f; unsigned int u; } v; v.f = f;
    unsigned int r = v.u + 0x7FFF + ((v.u >> 16) & 1);
    return (unsigned short)(r >> 16);
}
__device__ __forceinline__ unsigned short flip16(unsigned short h) {  // order-preserving f16->u16
    return h ^ ((h & 0x8000) ? 0xFFFFu : 0x8000u);
}
__device__ __forceinline__ float val16(unsigned int k) {       // inverse of flip16, as float
    unsigned short f = (unsigned short)k;
    unsigned short orig = (f & 0x8000) ? (unsigned short)(f ^ 0x8000) : (unsigned short)(~f);
    return __half2float(__ushort_as_half(orig));
}

// ---------------------------------------------------------------- K0: transpose + bf16 + norms
__global__ __launch_bounds__(256) void k_prep(const float* __restrict__ x,
                                              float* __restrict__ XTf,
                                              unsigned short* __restrict__ XTh,
                                              float* __restrict__ xx) {
    __shared__ float xs[64][65];
    const int tid = threadIdx.x;
    const int b = blockIdx.x >> 6, n0 = (blockIdx.x & 63) << 6;
    const float* xb = x + (size_t)b * C_ * N_;
    #pragma unroll
    for (int it = 0; it < 16; it++) {
        int id = it * 256 + tid; int c = id >> 6, nl = id & 63;
        xs[c][nl] = xb[c * N_ + n0 + nl];
    }
    __syncthreads();
    #pragma unroll
    for (int it = 0; it < 4; it++) {
        int flat = it * 256 + tid; int row = flat >> 4, f4 = flat & 15;
        float v0 = xs[f4*4+0][row], v1 = xs[f4*4+1][row], v2 = xs[f4*4+2][row], v3 = xs[f4*4+3][row];
        size_t base = ((size_t)(b * N_ + n0 + row)) * 64 + f4 * 4;
        float4 fv; fv.x = v0; fv.y = v1; fv.z = v2; fv.w = v3;
        *reinterpret_cast<float4*>(XTf + base) = fv;
        ushort4 hv; hv.x = f2bf(v0); hv.y = f2bf(v1); hv.z = f2bf(v2); hv.w = f2bf(v3);
        *reinterpret_cast<ushort4*>(XTh + base) = hv;
    }
    if (tid < 64) {
        float s = 0.f;
        #pragma unroll
        for (int c = 0; c < 64; c++) { float v = xs[c][tid]; s = fmaf(v, v, s); }
        xx[b * N_ + n0 + tid] = s;
    }
}

// ---------------------------------------------------------------- K1: MFMA approx distances, lane-owns-row selection
__global__ __launch_bounds__(256) void k_knn3(const unsigned short* __restrict__ XTh,
                                              const float* __restrict__ xx,
                                              unsigned short* __restrict__ cands,
                                              int* __restrict__ ccnt) {
    __shared__ __align__(16) unsigned short Bt[2][4096];   // 64x64 bf16 tiles, XOR-swizzled, dbuf
    __shared__ __align__(16) float xxc[2][64];
    __shared__ unsigned int buf[64 * BSTRIDE];             // per-row candidate keys
    __shared__ int cnt[64];
    __shared__ int cnt2[64];

    const int tid = threadIdx.x;
    const int wid = tid >> 6, lane = tid & 63;
    const int g = lane >> 4, lr = lane & 15;
    const int b = blockIdx.x >> 6, rb = blockIdx.x & 63;
    const int n0 = rb << 6;
    const unsigned short* Xb = XTh + (size_t)b * N_ * 64;
    const float* xxb = xx + b * N_;
    const int row = (wid << 4) + lr;           // block-local output row owned by this lane
    unsigned int* brow = &buf[row * BSTRIDE];

    // stage block's own 64 rows into Bt[0] (also serves as diagonal tile t=0)
    #pragma unroll
    for (int it = 0; it < 2; it++) {
        int u = it * 256 + tid;
        uint4 gv = *reinterpret_cast<const uint4*>(reinterpret_cast<const char*>(Xb) + (size_t)n0 * 128 + (size_t)u * 16);
        int r = u >> 3, cc = u & 7;
        *reinterpret_cast<uint4*>(reinterpret_cast<char*>(Bt[0]) + r * 128 + ((cc * 16) ^ ((r & 7) << 4))) = gv;
    }
    if (tid < 64) { xxc[0][tid] = xxb[n0 + tid]; cnt[tid] = 0; }
    __syncthreads();

    // B fragment = own row, register-resident for whole sweep
    bf16x8 bfr[2];
    #pragma unroll
    for (int kf = 0; kf < 2; kf++)
        bfr[kf] = *reinterpret_cast<const bf16x8*>(reinterpret_cast<const char*>(Bt[0]) + row * 128 + ((((kf << 6)) + (g << 4)) ^ ((row & 7) << 4)));
    const float cb = -xxb[n0 + row];           // -||x_n||^2
    float thr = -3.0e38f;

    // Race-free wave-parallel compaction (16 rows x 4 lanes each):
    // 1) slurp my stride-4 slice of keys into STATICALLY-indexed registers
    // 2) binary-search largest 16-bit prefix T with count>=K (from registers)
    // 3) rewrite buffer from registers (no LDS reads during writes), two-priority
    //    emit: core (>= T) first, margin second -> top-20-by-approx always emitted.
    auto compact = [&](bool emit, int iters) {
        int n = cnt[row]; if (n > CAPK) n = CAPK;              // clamp (appends may overshoot)
        unsigned int kr[CAPK / 4];
        #pragma unroll
        for (int s = 0; s < CAPK / 4; s++) {
            int j = 4 * s + g;
            kr[s] = (j < n) ? brow[j] : 0u;                    // sentinel 0 never passes mid>=1
        }
        int lo = 0, hi = 65536;
        for (int it = 0; it < iters; ++it) {
            int mid = (lo + hi) >> 1;
            unsigned int mk = (unsigned int)mid << 16;
            int c = 0;
            #pragma unroll
            for (int s = 0; s < CAPK / 4; s++) c += (kr[s] >= mk) ? 1 : 0;
            c += __shfl_xor(c, 16);
            c += __shfl_xor(c, 32);
            if (c >= K_) lo = mid; else hi = mid;
        }
        float nthr = val16((unsigned int)lo) - MARGIN;
        unsigned int kthr = ((unsigned int)flip16(__half_as_ushort(__float2half(nthr)))) << 16;
        if (g == 0) cnt2[row] = 0;
        lds_fence();
        const size_t grow = (size_t)(b * N_ + n0 + row);
        #pragma unroll
        for (int s = 0; s < CAPK / 4; s++) {                   // pass 1: core (>= lo prefix)
            int j = 4 * s + g;
            if (j < n && (kr[s] >> 16) >= (unsigned int)lo) {
                int p = atomicAdd(&cnt2[row], 1);
                if (p < CAPK) brow[p] = kr[s];
                if (emit && p < RCAP) cands[grow * RCAP + p] = (unsigned short)(kr[s] & 0xFFFu);
            }
        }
        #pragma unroll
        for (int s = 0; s < CAPK / 4; s++) {                   // pass 2: margin zone
            int j = 4 * s + g;
            if (j < n && (kr[s] >> 16) < (unsigned int)lo && kr[s] >= kthr) {
                int p = atomicAdd(&cnt2[row], 1);
                if (p < CAPK) brow[p] = kr[s];
                if (emit && p < RCAP) cands[grow * RCAP + p] = (unsigned short)(kr[s] & 0xFFFu);
            }
        }
        lds_fence();
        if (g == 0) {
            int nc = cnt2[row];
            cnt[row] = nc < CAPK ? nc : CAPK;
            if (emit) ccnt[grow] = nc < RCAP ? nc : RCAP;
        }
        thr = nthr;
        lds_fence();
    };

    int mt = rb;
    for (int t = 0; t < NT; t++) {
        const int cur = t & 1, nxt = cur ^ 1;
        const int m0 = mt << 6;
        // prefetch next tile (consumed after epilogue -> latency hidden)
        uint4 g0, g1; float xcn = 0.f;
        if (t + 1 < NT) {
            const int m0n = ((rb + t + 1) & 63) << 6;
            g0 = *reinterpret_cast<const uint4*>(reinterpret_cast<const char*>(Xb) + (size_t)m0n * 128 + (size_t)tid * 16);
            g1 = *reinterpret_cast<const uint4*>(reinterpret_cast<const char*>(Xb) + (size_t)m0n * 128 + (size_t)(256 + tid) * 16);
            if (tid < 64) xcn = xxb[m0n + tid];
        }
        // A fragments (streamed m-tile)
        bf16x8 af[4][2];
        #pragma unroll
        for (int rt = 0; rt < 4; rt++)
            #pragma unroll
            for (int kf = 0; kf < 2; kf++) {
                int r = rt * 16 + lr;
                af[rt][kf] = *reinterpret_cast<const bf16x8*>(reinterpret_cast<const char*>(Bt[cur]) + r * 128 + ((((kf << 6)) + (g << 4)) ^ ((r & 7) << 4)));
            }
        f32x4 acc[4];
        #pragma unroll
        for (int rt = 0; rt < 4; rt++) {
            acc[rt] = {0.f, 0.f, 0.f, 0.f};
            acc[rt] = __builtin_amdgcn_mfma_f32_16x16x32_bf16(af[rt][0], bfr[0], acc[rt], 0, 0, 0);
            acc[rt] = __builtin_amdgcn_mfma_f32_16x16x32_bf16(af[rt][1], bfr[1], acc[rt], 0, 0, 0);
        }
        // epilogue: nd = 2*dot - xx_n - xx_m for 16 m's of MY row; threshold-append
        int mask = 0;
        float nd[4][4];
        #pragma unroll
        for (int rt = 0; rt < 4; rt++) {
            float4 xm = *reinterpret_cast<const float4*>(&xxc[cur][rt * 16 + g * 4]);
            float xmv[4] = {xm.x, xm.y, xm.z, xm.w};
            #pragma unroll
            for (int q = 0; q < 4; q++) {
                float v = fmaf(2.f, acc[rt][q], cb) - xmv[q];
                nd[rt][q] = v;
                mask |= (v > thr) ? (1 << (rt * 4 + q)) : 0;
            }
        }
        if (mask) {
            int pos = atomicAdd(&cnt[row], __popc(mask));
            #pragma unroll
            for (int rt = 0; rt < 4; rt++)
                #pragma unroll
                for (int q = 0; q < 4; q++)
                    if (mask & (1 << (rt * 4 + q))) {
                        if (pos < CAPK) {
                            int mg = m0 + rt * 16 + g * 4 + q;
                            unsigned int key = ((unsigned int)flip16(__half_as_ushort(__float2half(nd[rt][q]))) << 16) | (unsigned int)mg;
                            brow[pos] = key;
                        }
                        pos++;
                    }
        }
        // stage prefetched tile into other buffer
        if (t + 1 < NT) {
            { int r = tid >> 3, cc = tid & 7;
              *reinterpret_cast<uint4*>(reinterpret_cast<char*>(Bt[nxt]) + r * 128 + ((cc * 16) ^ ((r & 7) << 4))) = g0; }
            { int u = 256 + tid; int r = u >> 3, cc = u & 7;
              *reinterpret_cast<uint4*>(reinterpret_cast<char*>(Bt[nxt]) + r * 128 + ((cc * 16) ^ ((r & 7) << 4))) = g1; }
            if (tid < 64) xxc[nxt][tid] = xcn;
        }
        lds_fence();
        bool need = cnt[row] > TRIG;
        if (t == 0 || __any(need)) compact(false, 13);
        __syncthreads();
        mt = (mt + 1) & 63;
    }
    lds_fence();
    compact(true, 16);                         // final: exact key threshold + emit
}

// ---------------------------------------------------------------- K2: exact fp32 re-rank of candidates -> top-20 indices
__global__ __launch_bounds__(256) void k_rerank(const float* __restrict__ XTf,
                                                const float* __restrict__ xx,
                                                const unsigned short* __restrict__ cands,
                                                const int* __restrict__ ccnt,
                                                int* __restrict__ idxb) {
    __shared__ float vals[4][RCAP];
    __shared__ int   ms[4][RCAP];
    __shared__ int   outIdx[4][K_];
    const int tid = threadIdx.x, wid = tid >> 6, lane = tid & 63;
    const size_t row = (size_t)blockIdx.x * 4 + wid;
    const int b = (int)(row >> 12), n = (int)(row & 4095);
    int cn = ccnt[row];
    cn = cn < 0 ? 0 : (cn > RCAP ? RCAP : cn);             // harden vs poison
    if (lane < K_) outIdx[wid][lane] = n;                  // hole-proof default (self)
    float nd = -FLT_MAX; int m = 0x7FFFFFFF;
    if (lane < cn) {
        m = cands[row * RCAP + lane] & 4095;
        const float* xn = XTf + ((size_t)b * N_ + n) * 64;
        const float* xm = XTf + ((size_t)b * N_ + m) * 64;
        float s = 0.f;
        #pragma unroll
        for (int i = 0; i < 16; i++) {
            float4 a  = *reinterpret_cast<const float4*>(xn + i * 4);
            float4 c2 = *reinterpret_cast<const float4*>(xm + i * 4);
            s = fmaf(a.x, c2.x, s); s = fmaf(a.y, c2.y, s);
            s = fmaf(a.z, c2.z, s); s = fmaf(a.w, c2.w, s);
        }
        nd = 2.f * s - xx[b * N_ + n] - xx[b * N_ + m];
        vals[wid][lane] = nd; ms[wid][lane] = m;
    }
    lds_fence();
    if (lane < cn) {
        int rank = 0;
        for (int j = 0; j < cn; j++) {
            float vj = vals[wid][j]; int mj = ms[wid][j];
            rank += (vj > nd) || (vj == nd && mj < m);
        }
        if (rank < K_) outIdx[wid][rank] = m;
    }
    lds_fence();
    if (lane < K_) idxb[row * K_ + lane] = outIdx[wid][lane];
}

// ---------------------------------------------------------------- K3: Pt = W1^T x, Qt = (W2-W1)^T x  (transposed [b][n][o])
__global__ __launch_bounds__(256) void k_pq(const float* __restrict__ x,
                                            const float* __restrict__ W,
                                            float* __restrict__ Pt,
                                            float* __restrict__ Qt) {
    __shared__ float2 Wl[64][65];
    __shared__ float  xT[64][64];
    const int tid = threadIdx.x;
    const int b  = blockIdx.x >> 6;
    const int n0 = (blockIdx.x & 63) * 64;
    const float* xb = x + (size_t)b * C_ * N_;

    #pragma unroll
    for (int kk = 0; kk < 16; kk++) {
        int id = tid + kk * 256;
        int c = id >> 6, o = id & 63;
        float w1 = W[o * 128 + c];
        float w2 = W[o * 128 + 64 + c];
        Wl[c][o] = make_float2(w1, w2 - w1);
    }
    #pragma unroll
    for (int kk = 0; kk < 16; kk++) {
        int id = tid + kk * 256;
        int c = id >> 6, nl = id & 63;
        xT[c][nl] = xb[c * N_ + n0 + nl];
    }
    __syncthreads();

    const int o = tid & 63, nq = tid >> 6;
    for (int s2 = 0; s2 < 4; s2++) {
        int gq = s2 * 4 + nq;
        float a1[4] = {0, 0, 0, 0}, a2[4] = {0, 0, 0, 0};
        #pragma unroll 8
        for (int c = 0; c < 64; c++) {
            float4 xv = *reinterpret_cast<const float4*>(&xT[c][gq * 4]);
            float2 wv = Wl[c][o];
            a1[0] = fmaf(wv.x, xv.x, a1[0]); a2[0] = fmaf(wv.y, xv.x, a2[0]);
            a1[1] = fmaf(wv.x, xv.y, a1[1]); a2[1] = fmaf(wv.y, xv.y, a2[1]);
            a1[2] = fmaf(wv.x, xv.z, a1[2]); a2[2] = fmaf(wv.y, xv.z, a2[2]);
            a1[3] = fmaf(wv.x, xv.w, a1[3]); a2[3] = fmaf(wv.y, xv.w, a2[3]);
        }
        #pragma unroll
        for (int gg = 0; gg < 4; gg++) {
            size_t base = ((size_t)(b * N_ + n0 + gq * 4 + gg)) * O_ + o;
            Pt[base] = a1[gg];
            Qt[base] = a2[gg];
        }
    }
}

// ---------------------------------------------------------------- K4: partial sums for BN stats
__global__ __launch_bounds__(256) void k_stats(const float* __restrict__ Pt,
                                               const float* __restrict__ Qt,
                                               const int* __restrict__ idxb,
                                               float* __restrict__ part) {
    const int tid = threadIdx.x;
    const int o = tid & 63, w = tid >> 6;
    float s = 0.f, q = 0.f;
    for (int it = 0; it < 16; it++) {
        int p = blockIdx.x * 4 + w + it * 2048;
        int b = p >> 12;
        const float* Ptb = Pt + (size_t)b * (N_ * O_);
        float Q = Qt[(size_t)p * O_ + o];
        const int* ip = idxb + (size_t)p * K_;
        #pragma unroll
        for (int k = 0; k < K_; k++) {
            int m = ip[k] & 4095;
            float v = Ptb[m * O_ + o] + Q;
            s += v;
            q = fmaf(v, v, q);
        }
    }
    __shared__ float ps[4][64], pq2[4][64];
    ps[w][o] = s; pq2[w][o] = q;
    __syncthreads();
    if (tid < 64) {
        float S  = ps[0][tid] + ps[1][tid] + ps[2][tid] + ps[3][tid];
        float Qq = pq2[0][tid] + pq2[1][tid] + pq2[2][tid] + pq2[3][tid];
        part[blockIdx.x * 128 + tid]      = S;
        part[blockIdx.x * 128 + 64 + tid] = Qq;
    }
}

// ---------------------------------------------------------------- K5: finalize mean/var -> scale/shift
__global__ void k_finalize(const float* __restrict__ part,
                           const float* __restrict__ gamma,
                           const float* __restrict__ beta,
                           float* __restrict__ ss) {
    int o = threadIdx.x;
    if (o < 64) {
        double s = 0.0, q = 0.0;
        for (int blk = 0; blk < 512; blk++) {
            s += part[blk * 128 + o];
            q += part[blk * 128 + 64 + o];
        }
        double M = (double)B_ * N_ * K_;
        double mean = s / M;
        double var = q / M - mean * mean;
        double inv = 1.0 / sqrt(var + (double)EPS_);
        double sc = (double)gamma[o] * inv;
        ss[o]      = (float)sc;
        ss[64 + o] = (float)((double)beta[o] - mean * sc);
    }
}

// ---------------------------------------------------------------- K6: normalized leaky-relu max over K, coalesced store
__global__ __launch_bounds__(256) void k_out(const float* __restrict__ Pt,
                                             const float* __restrict__ Qt,
                                             const int* __restrict__ idxb,
                                             const float* __restrict__ ss,
                                             float* __restrict__ out) {
    __shared__ float res[64][65];
    const int tid = threadIdx.x;
    const int o = tid & 63, w = tid >> 6;
    const int b  = blockIdx.x >> 6;
    const int n0 = (blockIdx.x & 63) * 64;
    const float sc = ss[o], sh = ss[64 + o];
    const float* Ptb = Pt + (size_t)b * (N_ * O_);
    for (int s2 = 0; s2 < 16; s2++) {
        int nl = s2 * 4 + w;
        int p = b * N_ + n0 + nl;
        float Q = Qt[(size_t)p * O_ + o];
        const int* ip = idxb + (size_t)p * K_;
        float best = -FLT_MAX;
        #pragma unroll
        for (int k = 0; k < K_; k++) {
            int m = ip[k] & 4095;
            float v = Ptb[m * O_ + o] + Q;
            float t2 = fmaf(v, sc, sh);
            t2 = t2 >= 0.f ? t2 : SLOPE_ * t2;
            best = fmaxf(best, t2);
        }
        res[nl][o] = best;
    }
    __syncthreads();
    const int j = tid & 63;
    const int ow = tid >> 6;
    for (int s2 = 0; s2 < 16; s2++) {
        int oo = s2 * 4 + ow;
        out[((size_t)(b * O_ + oo)) * N_ + n0 + j] = res[j][oo];
    }
}

// ---------------------------------------------------------------- launch
extern "C" void kernel_launch(void* const* d_in, const int* in_sizes, int n_in,
                              void* d_out, int out_size, void* d_ws, size_t ws_size,
                              hipStream_t stream) {
    const float* x     = (const float*)d_in[0];
    const float* W     = (const float*)d_in[1];
    const float* gamma = (const float*)d_in[2];
    const float* beta  = (const float*)d_in[3];

    float* ws = (float*)d_ws;
    int*   idxb = (int*)(ws + WS_IDXB);
    float* XTf  = ws + WS_R1;                              // aliased by Pt later
    float* R2   = ws + WS_R2;                              // aliased by Qt later
    unsigned short* XTh   = (unsigned short*)(R2 + R2_XTH);
    unsigned short* cands = (unsigned short*)(R2 + R2_CANDS);
    int*   ccnt = (int*)(R2 + R2_CCNT);
    float* xx   = R2 + R2_XX;
    float* Pt   = ws + WS_R1;
    float* Qt   = ws + WS_R2;
    float* part = ws + WS_PART;
    float* ss   = ws + WS_SS;
    float* out  = (float*)d_out;

    hipLaunchKernelGGL(k_prep,     dim3(512),  dim3(256), 0, stream, x, XTf, XTh, xx);
    hipLaunchKernelGGL(k_knn3,     dim3(512),  dim3(256), 0, stream, XTh, xx, cands, ccnt);
    hipLaunchKernelGGL(k_rerank,   dim3(8192), dim3(256), 0, stream, XTf, xx, cands, ccnt, idxb);
    hipLaunchKernelGGL(k_pq,       dim3(512),  dim3(256), 0, stream, x, W, Pt, Qt);
    hipLaunchKernelGGL(k_stats,    dim3(512),  dim3(256), 0, stream, Pt, Qt, idxb, part);
    hipLaunchKernelGGL(k_finalize, dim3(1),    dim3(64),  0, stream, part, gamma, beta, ss);
    hipLaunchKernelGGL(k_out,      dim3(512),  dim3(256), 0, stream, Pt, Qt, idxb, ss, out);
}